// Round 5
// baseline (128.125 us; speedup 1.0000x reference)
//
#include <hip/hip_runtime.h>
#include <hip/hip_bf16.h>

#define N_SEQ 2048
#define DMODEL 1024
#define NHEAD 16
#define HD 64
#define NREL 199   // 2*MAX_REL-1

typedef __bf16 bf16x8 __attribute__((ext_vector_type(8)));
typedef float f32x4 __attribute__((ext_vector_type(4)));

__device__ __forceinline__ bf16x8 cvt8(float4 a, float4 b) {
    bf16x8 r;
    r[0] = (__bf16)a.x; r[1] = (__bf16)a.y; r[2] = (__bf16)a.z; r[3] = (__bf16)a.w;
    r[4] = (__bf16)b.x; r[5] = (__bf16)b.y; r[6] = (__bf16)b.z; r[7] = (__bf16)b.w;
    return r;
}

#define MFMA16(A, B, C) __builtin_amdgcn_mfma_f32_16x16x32_bf16(A, B, C, 0, 0, 0)

// async 16B/lane global->LDS. LDS dest = wave-uniform base + lane*16.
__device__ __forceinline__ void async_copy16(void* lds, const void* g) {
    __builtin_amdgcn_global_load_lds(
        (__attribute__((address_space(1))) unsigned int*)g,
        (__attribute__((address_space(3))) unsigned int*)lds, 16, 0, 0);
}

// ---------------------------------------------------------------------------
// fp32 -> bf16 conversion prepass: x, qkv_w, rel_emb (proj_w folded into attn
// tail blocks). rel bf16 removes the 32x-redundant per-attn-block conversion.
__global__ __launch_bounds__(256) void cvt3(
    const float* __restrict__ a, __bf16* __restrict__ ao, int na,
    const float* __restrict__ b, __bf16* __restrict__ bo, int nb,
    const float* __restrict__ c, __bf16* __restrict__ co, int nc)
{
    int i = (blockIdx.x * blockDim.x + threadIdx.x) * 8;
    if (i >= na + nb + nc) return;
    const float* src; __bf16* dst;
    if (i < na)              { src = a + i;            dst = ao + i; }
    else if (i - na < nb)    { src = b + (i - na);     dst = bo + (i - na); }
    else                     { src = c + (i - na - nb); dst = co + (i - na - nb); }
    float4 f0 = ((const float4*)src)[0];
    float4 f1 = ((const float4*)src)[1];
    *(bf16x8*)dst = cvt8(f0, f1);
}

// ---------------------------------------------------------------------------
// bf16 GEMM (R1 winner, unchanged): software-pipelined K-loop, LDS double
// buffer, async global->LDS issued after the barrier so loads stay in flight
// across the compute phase. XOR-swizzled packed LDS ds_read_b128.
template<int BM, int BN, bool OUT_BF16>
__global__ __launch_bounds__(256) void gemm_db(
    const __bf16* __restrict__ A,
    const __bf16* __restrict__ W,
    const float* __restrict__ bias,
    void* __restrict__ Cout,
    int lda, int Nc, int K, int ldc)
{
    constexpr int RT = BM + BN;
    constexpr int WM = BM / 2, WN = BN / 2;
    constexpr int MI = WM / 16, NI = WN / 16;
    constexpr int CHUNKS = RT / 4 / 8;

    __shared__ __bf16 s[2][RT][64];

    const int tid  = threadIdx.x;
    const int wid  = tid >> 6;
    const int lane = tid & 63;
    const int quad = lane >> 4;
    const int l15  = lane & 15;
    const int wm   = (wid >> 1) * WM;
    const int wn   = (wid & 1) * WN;
    const int bm   = blockIdx.y * BM;
    const int bn   = blockIdx.x * BN;

    const int lrow = lane >> 3;
    const int lcb  = ((lane & 7) ^ lrow) * 8;

    f32x4 acc[MI][NI] = {};

    auto stage = [&](int buf, int k0) {
        #pragma unroll
        for (int c = 0; c < CHUNKS; c++) {
            const int r0 = wid * (RT / 4) + c * 8;
            const __bf16* src = (r0 < BM)
                ? A + (size_t)(bm + r0 + lrow) * lda + k0 + lcb
                : W + (size_t)(bn + (r0 - BM) + lrow) * K + k0 + lcb;
            async_copy16(&s[buf][r0][0], src);
        }
    };

    stage(0, 0);
    int cur = 0;
    for (int k0 = 0; k0 < K; k0 += 64) {
        __syncthreads();                          // drains loads into s[cur]
        if (k0 + 64 < K) stage(cur ^ 1, k0 + 64); // in flight across compute

        #pragma unroll
        for (int half = 0; half < 2; half++) {
            bf16x8 af[MI], bfr[NI];
            #pragma unroll
            for (int mi = 0; mi < MI; mi++) {
                int ar = wm + mi * 16 + l15;
                af[mi] = *(const bf16x8*)&s[cur][ar][((quad + 4 * half) ^ (ar & 7)) * 8];
            }
            #pragma unroll
            for (int ni = 0; ni < NI; ni++) {
                int br = BM + wn + ni * 16 + l15;
                bfr[ni] = *(const bf16x8*)&s[cur][br][((quad + 4 * half) ^ (br & 7)) * 8];
            }
            #pragma unroll
            for (int mi = 0; mi < MI; mi++)
                #pragma unroll
                for (int ni = 0; ni < NI; ni++)
                    acc[mi][ni] = MFMA16(af[mi], bfr[ni], acc[mi][ni]);
        }
        cur ^= 1;
    }

    #pragma unroll
    for (int ni = 0; ni < NI; ni++) {
        int col = bn + wn + ni * 16 + l15;
        float bv = bias[col];
        #pragma unroll
        for (int mi = 0; mi < MI; mi++)
            #pragma unroll
            for (int ri = 0; ri < 4; ri++) {
                int row = bm + wm + mi * 16 + quad * 4 + ri;
                float v = acc[mi][ni][ri] + bv;
                if (OUT_BF16)
                    reinterpret_cast<__bf16*>(Cout)[(size_t)row * ldc + col] = (__bf16)v;
                else
                    reinterpret_cast<float*>(Cout)[(size_t)row * ldc + col] = v;
            }
    }
}

// ---------------------------------------------------------------------------
// MFMA flash-band attention (R4 winner + bf16-rel prologue + P-phase setprio):
// static 52 KB LDS (3 blocks/CU), register-prefetch k/v double-buffering,
// no-rescale softmax, ones-column row sums, s_setprio(1) around MFMA
// clusters. 16 tail blocks convert proj_w fp32->bf16 in attn's shadow.
__global__ __launch_bounds__(256) void attn_band_mfma(
    __hip_bfloat16* __restrict__ qkv,   // bf16 [2048][3072]
    const __bf16* __restrict__ rel_b,   // bf16 [16][199][64] (pre-converted)
    const float* __restrict__ pw,       // fp32 proj_w [1024*1024]
    __bf16* __restrict__ pwb)           // bf16 proj_w out
{
    if (blockIdx.x >= NHEAD * 32) {
        // proj_w conversion: 16 blocks x 65536 elems (pure streaming)
        const int b = blockIdx.x - NHEAD * 32;
        const int base = b * 65536 + threadIdx.x * 8;
        #pragma unroll 4
        for (int it = 0; it < 32; it++) {
            int i = base + it * 2048;
            float4 f0 = ((const float4*)(pw + i))[0];
            float4 f1 = ((const float4*)(pw + i))[1];
            *(bf16x8*)(pwb + i) = cvt8(f0, f1);
        }
        return;
    }

    __shared__ __align__(16) char smem[53248];
    __bf16 (*q_s)[72]   = (__bf16(*)[72])smem;          // dead after frag hoist
    __bf16 (*p_s)[72]   = (__bf16(*)[72])smem;          // overlays q_s
    __bf16 (*P_s)[200]  = (__bf16(*)[200])(smem + 9216);
    __bf16 (*relc)[72]  = (__bf16(*)[72])(smem + 34816);
    __bf16 (*k_s)[72]   = (__bf16(*)[72])(smem + 34816);
    __bf16 (*v_s)[72]   = (__bf16(*)[72])(smem + 34816 + 9216);

    const int tid  = threadIdx.x;
    const int wid  = tid >> 6;
    const int lane = tid & 63;
    const int quad = lane >> 4;
    const int l15  = lane & 15;
    const int h    = blockIdx.x >> 5;
    const int q0   = (blockIdx.x & 31) * 64;
    const int srow = tid >> 2;
    const int sq   = (tid & 3) * 16;

    const int j_lo   = (q0 - 99 > 0) ? (q0 - 99) : 0;
    const int j_hi   = (q0 + 162 < N_SEQ - 1) ? (q0 + 162) : (N_SEQ - 1);
    const int ntiles = (j_hi - j_lo + 64) >> 6;

    // tile-0 k/v prefetch; s_waitcnt lands after the whole P phase
    uint4 kr0, kr1, vr0, vr1;
    {
        int jr = j_lo + srow; if (jr > N_SEQ - 1) jr = N_SEQ - 1;
        const uint4* ks = (const uint4*)(qkv + (size_t)jr * 3072 + 1024 + h * HD + sq);
        kr0 = ks[0]; kr1 = ks[1];
        const uint4* vs = (const uint4*)(qkv + (size_t)jr * 3072 + 2048 + h * HD + sq);
        vr0 = vs[0]; vr1 = vs[1];
    }

    {
        const __hip_bfloat16* src = qkv + (size_t)(q0 + srow) * 3072 + h * HD + sq;
        uint4 u0 = ((const uint4*)src)[0];
        uint4 u1 = ((const uint4*)src)[1];
        *(uint4*)&q_s[srow][sq]     = u0;
        *(uint4*)&q_s[srow][sq + 8] = u1;
    }
    // relc fill part 1: rows 0..111, bf16 source (1 uint4 load per 8 elems)
    for (int idx = tid; idx < 112 * 4; idx += 256) {
        int er = idx >> 2, ec = (idx & 3) * 16;
        const uint4* s = (const uint4*)(rel_b + ((size_t)h * NREL + er) * HD + ec);
        *(uint4*)&relc[er][ec]     = s[0];
        *(uint4*)&relc[er][ec + 8] = s[1];
    }
    __syncthreads();

    const bf16x8 aq0 = *(const bf16x8*)&q_s[wid * 16 + l15][quad * 8];
    const bf16x8 aq1 = *(const bf16x8*)&q_s[wid * 16 + l15][quad * 8 + 32];

    #pragma unroll
    for (int t = 0; t < 7; t++) {
        f32x4 pacc = {};
        bf16x8 b0 = *(const bf16x8*)&relc[t * 16 + l15][quad * 8];
        bf16x8 b1 = *(const bf16x8*)&relc[t * 16 + l15][quad * 8 + 32];
        __builtin_amdgcn_s_setprio(1);
        pacc = MFMA16(aq0, b0, pacc);
        pacc = MFMA16(aq1, b1, pacc);
        __builtin_amdgcn_s_setprio(0);
        #pragma unroll
        for (int ri = 0; ri < 4; ri++)
            P_s[wid * 16 + quad * 4 + ri][t * 16 + l15] = (__bf16)pacc[ri];
    }
    __syncthreads();

    // relc fill part 2: rows 112..198 (clamped), bf16 source
    for (int idx = tid; idx < 96 * 4; idx += 256) {
        int er = 112 + (idx >> 2); if (er > NREL - 1) er = NREL - 1;
        int ec = (idx & 3) * 16;
        const uint4* s = (const uint4*)(rel_b + ((size_t)h * NREL + er) * HD + ec);
        *(uint4*)&relc[idx >> 2][ec]     = s[0];
        *(uint4*)&relc[idx >> 2][ec + 8] = s[1];
    }
    __syncthreads();

    #pragma unroll
    for (int t = 7; t < 13; t++) {
        f32x4 pacc = {};
        bf16x8 b0 = *(const bf16x8*)&relc[t * 16 + l15 - 112][quad * 8];
        bf16x8 b1 = *(const bf16x8*)&relc[t * 16 + l15 - 112][quad * 8 + 32];
        __builtin_amdgcn_s_setprio(1);
        pacc = MFMA16(aq0, b0, pacc);
        pacc = MFMA16(aq1, b1, pacc);
        __builtin_amdgcn_s_setprio(0);
        #pragma unroll
        for (int ri = 0; ri < 4; ri++) {
            int col = t * 16 + l15;
            if (col < NREL)
                P_s[wid * 16 + quad * 4 + ri][col] = (__bf16)pacc[ri];
        }
    }

    bf16x8 bones;
    {
        __bf16 o = (l15 == 0) ? (__bf16)1.0f : (__bf16)0.0f;
        #pragma unroll
        for (int i = 0; i < 8; i++) bones[i] = o;
    }

    f32x4 O[4] = {};
    f32x4 Osum = {};

    for (int t = 0; t < ntiles; t++) {
        __syncthreads();

        *(uint4*)&k_s[srow][sq]     = kr0;
        *(uint4*)&k_s[srow][sq + 8] = kr1;
        {
            __bf16 vtmp[16];
            *(uint4*)&vtmp[0] = vr0; *(uint4*)&vtmp[8] = vr1;
            #pragma unroll
            for (int i = 0; i < 16; i++) v_s[sq + i][srow] = vtmp[i];  // V^T
        }
        __syncthreads();

        if (t + 1 < ntiles) {
            int jr = j_lo + (t + 1) * 64 + srow; if (jr > N_SEQ - 1) jr = N_SEQ - 1;
            const uint4* ks = (const uint4*)(qkv + (size_t)jr * 3072 + 1024 + h * HD + sq);
            kr0 = ks[0]; kr1 = ks[1];
            const uint4* vs = (const uint4*)(qkv + (size_t)jr * 3072 + 2048 + h * HD + sq);
            vr0 = vs[0]; vr1 = vs[1];
        }

        const int j0 = j_lo + t * 64;

        f32x4 S[4] = {};
        __builtin_amdgcn_s_setprio(1);
        #pragma unroll
        for (int nt = 0; nt < 4; nt++) {
            bf16x8 b0 = *(const bf16x8*)&k_s[nt * 16 + l15][quad * 8];
            bf16x8 b1 = *(const bf16x8*)&k_s[nt * 16 + l15][quad * 8 + 32];
            S[nt] = MFMA16(aq0, b0, S[nt]);
            S[nt] = MFMA16(aq1, b1, S[nt]);
        }
        __builtin_amdgcn_s_setprio(0);

        #pragma unroll
        for (int nt = 0; nt < 4; nt++) {
            int jg = j0 + nt * 16 + l15;
            #pragma unroll
            for (int ri = 0; ri < 4; ri++) {
                int r_loc = wid * 16 + quad * 4 + ri;
                int e = jg - (q0 + r_loc) + 99;
                float v = -3.0e38f;
                if ((unsigned)e < (unsigned)NREL && jg < N_SEQ)
                    v = S[nt][ri] * 0.125f + (float)P_s[r_loc][e];
                float p = __expf(v);   // masked -> 0
                p_s[r_loc][nt * 16 + l15] = (__bf16)p;   // wave-private stripe
            }
        }

        bf16x8 ap0 = *(const bf16x8*)&p_s[wid * 16 + l15][quad * 8];
        bf16x8 ap1 = *(const bf16x8*)&p_s[wid * 16 + l15][quad * 8 + 32];
        __builtin_amdgcn_s_setprio(1);
        #pragma unroll
        for (int nt = 0; nt < 4; nt++) {
            bf16x8 b0 = *(const bf16x8*)&v_s[nt * 16 + l15][quad * 8];
            bf16x8 b1 = *(const bf16x8*)&v_s[nt * 16 + l15][quad * 8 + 32];
            O[nt] = MFMA16(ap0, b0, O[nt]);
            O[nt] = MFMA16(ap1, b1, O[nt]);
        }
        Osum = MFMA16(ap0, bones, Osum);
        Osum = MFMA16(ap1, bones, Osum);
        __builtin_amdgcn_s_setprio(0);
    }

    #pragma unroll
    for (int ri = 0; ri < 4; ri++) {
        float s = __shfl(Osum[ri], (lane & 48), 64);
        float inv = 1.0f / s;
        #pragma unroll
        for (int nt = 0; nt < 4; nt++) {
            int r = q0 + wid * 16 + quad * 4 + ri;
            qkv[(size_t)r * 3072 + h * HD + nt * 16 + l15] =
                __float2bfloat16(O[nt][ri] * inv);
        }
    }
}

extern "C" void kernel_launch(void* const* d_in, const int* in_sizes, int n_in,
                              void* d_out, int out_size, void* d_ws, size_t ws_size,
                              hipStream_t stream)
{
    (void)out_size; (void)ws_size; (void)n_in;

    const float *x = nullptr, *qkv_w = nullptr, *qkv_b = nullptr;
    const float *proj_w = nullptr, *proj_b = nullptr, *rel = nullptr;
    for (int i = 0; i < 6; i++) {
        switch (in_sizes[i]) {
            case 2097152: x      = (const float*)d_in[i]; break;
            case 3145728: qkv_w  = (const float*)d_in[i]; break;
            case 3072:    qkv_b  = (const float*)d_in[i]; break;
            case 1048576: proj_w = (const float*)d_in[i]; break;
            case 1024:    proj_b = (const float*)d_in[i]; break;
            case 203776:  rel    = (const float*)d_in[i]; break;
            default: break;
        }
    }

    char* ws = (char*)d_ws;
    __hip_bfloat16* qkv = (__hip_bfloat16*)ws;              // [2048][3072] 12.58 MB
    __bf16* xb   = (__bf16*)(ws + 12582912);                // x bf16      4.19 MB
    __bf16* wb   = (__bf16*)(ws + 16777216);                // qkv_w bf16  6.29 MB
    __bf16* pwb  = (__bf16*)(ws + 23068672);                // proj_w bf16 2.10 MB
    __bf16* relb = (__bf16*)(ws + 25165824);                // rel bf16    0.41 MB
    float* out = (float*)d_out;                             // [2048][1024] fp32

    // x + qkv_w + rel_emb conversion (proj_w folded into attn tail blocks)
    const int ncvt = 2097152 + 3145728 + 203776;
    cvt3<<<dim3((ncvt / 8 + 255) / 256), 256, 0, stream>>>(
        x, xb, 2097152, qkv_w, wb, 3145728, rel, relb, 203776);
    gemm_db<128, 96, true><<<dim3(3072 / 96, N_SEQ / 128), 256, 0, stream>>>(
        xb, wb, qkv_b, (void*)qkv, DMODEL, 3072, DMODEL, 3072);
    attn_band_mfma<<<dim3(NHEAD * (N_SEQ / 64) + 16), 256, 0, stream>>>(
        qkv, relb, proj_w, pwb);
    gemm_db<64, 64, false><<<dim3(DMODEL / 64, N_SEQ / 64), 256, 0, stream>>>(
        (const __bf16*)qkv, pwb, proj_b, (void*)out, 3072, DMODEL, DMODEL, DMODEL);
}

// Round 6
// 123.449 us; speedup vs baseline: 1.0379x; 1.0379x over previous
//
#include <hip/hip_runtime.h>
#include <hip/hip_bf16.h>

#define N_SEQ 2048
#define DMODEL 1024
#define NHEAD 16
#define HD 64
#define NREL 199   // 2*MAX_REL-1

typedef __bf16 bf16x8 __attribute__((ext_vector_type(8)));
typedef float f32x4 __attribute__((ext_vector_type(4)));

__device__ __forceinline__ bf16x8 cvt8(float4 a, float4 b) {
    bf16x8 r;
    r[0] = (__bf16)a.x; r[1] = (__bf16)a.y; r[2] = (__bf16)a.z; r[3] = (__bf16)a.w;
    r[4] = (__bf16)b.x; r[5] = (__bf16)b.y; r[6] = (__bf16)b.z; r[7] = (__bf16)b.w;
    return r;
}

#define MFMA16(A, B, C) __builtin_amdgcn_mfma_f32_16x16x32_bf16(A, B, C, 0, 0, 0)

// async 16B/lane global->LDS. LDS dest = wave-uniform base + lane*16.
__device__ __forceinline__ void async_copy16(void* lds, const void* g) {
    __builtin_amdgcn_global_load_lds(
        (__attribute__((address_space(1))) unsigned int*)g,
        (__attribute__((address_space(3))) unsigned int*)lds, 16, 0, 0);
}

// ---------------------------------------------------------------------------
// fp32 -> bf16 conversion prepass: x, qkv_w (proj_w folded into attn tail).
__global__ __launch_bounds__(256) void cvt3(
    const float* __restrict__ a, __bf16* __restrict__ ao, int na,
    const float* __restrict__ b, __bf16* __restrict__ bo, int nb,
    const float* __restrict__ c, __bf16* __restrict__ co)
{
    int i = (blockIdx.x * blockDim.x + threadIdx.x) * 8;
    const float* src; __bf16* dst;
    if (i < na)              { src = a + i;            dst = ao + i; }
    else if (i - na < nb)    { src = b + (i - na);     dst = bo + (i - na); }
    else                     { src = c + (i - na - nb); dst = co + (i - na - nb); }
    float4 f0 = ((const float4*)src)[0];
    float4 f1 = ((const float4*)src)[1];
    *(bf16x8*)dst = cvt8(f0, f1);
}

// ---------------------------------------------------------------------------
// bf16 GEMM (R1 winner, unchanged): software-pipelined K-loop, LDS double
// buffer, async global->LDS issued after the barrier so loads stay in flight
// across the compute phase. XOR-swizzled packed LDS ds_read_b128.
template<int BM, int BN, bool OUT_BF16>
__global__ __launch_bounds__(256) void gemm_db(
    const __bf16* __restrict__ A,
    const __bf16* __restrict__ W,
    const float* __restrict__ bias,
    void* __restrict__ Cout,
    int lda, int Nc, int K, int ldc)
{
    constexpr int RT = BM + BN;
    constexpr int WM = BM / 2, WN = BN / 2;
    constexpr int MI = WM / 16, NI = WN / 16;
    constexpr int CHUNKS = RT / 4 / 8;

    __shared__ __bf16 s[2][RT][64];

    const int tid  = threadIdx.x;
    const int wid  = tid >> 6;
    const int lane = tid & 63;
    const int quad = lane >> 4;
    const int l15  = lane & 15;
    const int wm   = (wid >> 1) * WM;
    const int wn   = (wid & 1) * WN;
    const int bm   = blockIdx.y * BM;
    const int bn   = blockIdx.x * BN;

    const int lrow = lane >> 3;
    const int lcb  = ((lane & 7) ^ lrow) * 8;

    f32x4 acc[MI][NI] = {};

    auto stage = [&](int buf, int k0) {
        #pragma unroll
        for (int c = 0; c < CHUNKS; c++) {
            const int r0 = wid * (RT / 4) + c * 8;
            const __bf16* src = (r0 < BM)
                ? A + (size_t)(bm + r0 + lrow) * lda + k0 + lcb
                : W + (size_t)(bn + (r0 - BM) + lrow) * K + k0 + lcb;
            async_copy16(&s[buf][r0][0], src);
        }
    };

    stage(0, 0);
    int cur = 0;
    for (int k0 = 0; k0 < K; k0 += 64) {
        __syncthreads();                          // drains loads into s[cur]
        if (k0 + 64 < K) stage(cur ^ 1, k0 + 64); // in flight across compute

        #pragma unroll
        for (int half = 0; half < 2; half++) {
            bf16x8 af[MI], bfr[NI];
            #pragma unroll
            for (int mi = 0; mi < MI; mi++) {
                int ar = wm + mi * 16 + l15;
                af[mi] = *(const bf16x8*)&s[cur][ar][((quad + 4 * half) ^ (ar & 7)) * 8];
            }
            #pragma unroll
            for (int ni = 0; ni < NI; ni++) {
                int br = BM + wn + ni * 16 + l15;
                bfr[ni] = *(const bf16x8*)&s[cur][br][((quad + 4 * half) ^ (br & 7)) * 8];
            }
            #pragma unroll
            for (int mi = 0; mi < MI; mi++)
                #pragma unroll
                for (int ni = 0; ni < NI; ni++)
                    acc[mi][ni] = MFMA16(af[mi], bfr[ni], acc[mi][ni]);
        }
        cur ^= 1;
    }

    #pragma unroll
    for (int ni = 0; ni < NI; ni++) {
        int col = bn + wn + ni * 16 + l15;
        float bv = bias[col];
        #pragma unroll
        for (int mi = 0; mi < MI; mi++)
            #pragma unroll
            for (int ri = 0; ri < 4; ri++) {
                int row = bm + wm + mi * 16 + quad * 4 + ri;
                float v = acc[mi][ni][ri] + bv;
                if (OUT_BF16)
                    reinterpret_cast<__bf16*>(Cout)[(size_t)row * ldc + col] = (__bf16)v;
                else
                    reinterpret_cast<float*>(Cout)[(size_t)row * ldc + col] = v;
            }
    }
}

// ---------------------------------------------------------------------------
// MFMA flash-band attention: round-12 winner structure (static 52 KB LDS,
// register-prefetch k/v double-buffering, no-rescale softmax, ones-column row
// sums) + s_setprio(1) around MFMA clusters (m191 regime: multiple
// independent blocks/CU at different phases). 16 tail blocks convert proj_w
// fp32->bf16 in attn's shadow.
__global__ __launch_bounds__(256) void attn_band_mfma(
    __hip_bfloat16* __restrict__ qkv,   // bf16 [2048][3072]
    const float* __restrict__ rel_emb,  // fp32 [16][199][64]
    const float* __restrict__ pw,       // fp32 proj_w [1024*1024]
    __bf16* __restrict__ pwb)           // bf16 proj_w out
{
    if (blockIdx.x >= NHEAD * 32) {
        // proj_w conversion: 16 blocks x 65536 elems (pure streaming)
        const int b = blockIdx.x - NHEAD * 32;
        const int base = b * 65536 + threadIdx.x * 8;
        #pragma unroll 4
        for (int it = 0; it < 32; it++) {
            int i = base + it * 2048;
            float4 f0 = ((const float4*)(pw + i))[0];
            float4 f1 = ((const float4*)(pw + i))[1];
            *(bf16x8*)(pwb + i) = cvt8(f0, f1);
        }
        return;
    }

    __shared__ __align__(16) char smem[53248];
    __bf16 (*q_s)[72]   = (__bf16(*)[72])smem;          // dead after frag hoist
    __bf16 (*p_s)[72]   = (__bf16(*)[72])smem;          // overlays q_s
    __bf16 (*P_s)[200]  = (__bf16(*)[200])(smem + 9216);
    __bf16 (*relc)[72]  = (__bf16(*)[72])(smem + 34816);
    __bf16 (*k_s)[72]   = (__bf16(*)[72])(smem + 34816);
    __bf16 (*v_s)[72]   = (__bf16(*)[72])(smem + 34816 + 9216);

    const int tid  = threadIdx.x;
    const int wid  = tid >> 6;
    const int lane = tid & 63;
    const int quad = lane >> 4;
    const int l15  = lane & 15;
    const int h    = blockIdx.x >> 5;
    const int q0   = (blockIdx.x & 31) * 64;
    const int srow = tid >> 2;
    const int sq   = (tid & 3) * 16;

    const int j_lo   = (q0 - 99 > 0) ? (q0 - 99) : 0;
    const int j_hi   = (q0 + 162 < N_SEQ - 1) ? (q0 + 162) : (N_SEQ - 1);
    const int ntiles = (j_hi - j_lo + 64) >> 6;

    // tile-0 k/v prefetch; s_waitcnt lands after the whole P phase
    uint4 kr0, kr1, vr0, vr1;
    {
        int jr = j_lo + srow; if (jr > N_SEQ - 1) jr = N_SEQ - 1;
        const uint4* ks = (const uint4*)(qkv + (size_t)jr * 3072 + 1024 + h * HD + sq);
        kr0 = ks[0]; kr1 = ks[1];
        const uint4* vs = (const uint4*)(qkv + (size_t)jr * 3072 + 2048 + h * HD + sq);
        vr0 = vs[0]; vr1 = vs[1];
    }

    {
        const __hip_bfloat16* src = qkv + (size_t)(q0 + srow) * 3072 + h * HD + sq;
        uint4 u0 = ((const uint4*)src)[0];
        uint4 u1 = ((const uint4*)src)[1];
        *(uint4*)&q_s[srow][sq]     = u0;
        *(uint4*)&q_s[srow][sq + 8] = u1;
    }
    for (int idx = tid; idx < 112 * 4; idx += 256) {
        int er = idx >> 2, ec = (idx & 3) * 16;
        const float4* s = (const float4*)(rel_emb + ((size_t)h * NREL + er) * HD + ec);
        float4 f0 = s[0], f1 = s[1], f2 = s[2], f3 = s[3];
        *(bf16x8*)&relc[er][ec]     = cvt8(f0, f1);
        *(bf16x8*)&relc[er][ec + 8] = cvt8(f2, f3);
    }
    __syncthreads();

    const bf16x8 aq0 = *(const bf16x8*)&q_s[wid * 16 + l15][quad * 8];
    const bf16x8 aq1 = *(const bf16x8*)&q_s[wid * 16 + l15][quad * 8 + 32];

    #pragma unroll
    for (int t = 0; t < 7; t++) {
        f32x4 pacc = {};
        bf16x8 b0 = *(const bf16x8*)&relc[t * 16 + l15][quad * 8];
        bf16x8 b1 = *(const bf16x8*)&relc[t * 16 + l15][quad * 8 + 32];
        pacc = MFMA16(aq0, b0, pacc);
        pacc = MFMA16(aq1, b1, pacc);
        #pragma unroll
        for (int ri = 0; ri < 4; ri++)
            P_s[wid * 16 + quad * 4 + ri][t * 16 + l15] = (__bf16)pacc[ri];
    }
    __syncthreads();

    for (int idx = tid; idx < 96 * 4; idx += 256) {
        int er = 112 + (idx >> 2); if (er > NREL - 1) er = NREL - 1;
        int ec = (idx & 3) * 16;
        const float4* s = (const float4*)(rel_emb + ((size_t)h * NREL + er) * HD + ec);
        float4 f0 = s[0], f1 = s[1], f2 = s[2], f3 = s[3];
        *(bf16x8*)&relc[idx >> 2][ec]     = cvt8(f0, f1);
        *(bf16x8*)&relc[idx >> 2][ec + 8] = cvt8(f2, f3);
    }
    __syncthreads();

    #pragma unroll
    for (int t = 7; t < 13; t++) {
        f32x4 pacc = {};
        bf16x8 b0 = *(const bf16x8*)&relc[t * 16 + l15 - 112][quad * 8];
        bf16x8 b1 = *(const bf16x8*)&relc[t * 16 + l15 - 112][quad * 8 + 32];
        pacc = MFMA16(aq0, b0, pacc);
        pacc = MFMA16(aq1, b1, pacc);
        #pragma unroll
        for (int ri = 0; ri < 4; ri++) {
            int col = t * 16 + l15;
            if (col < NREL)
                P_s[wid * 16 + quad * 4 + ri][col] = (__bf16)pacc[ri];
        }
    }

    bf16x8 bones;
    {
        __bf16 o = (l15 == 0) ? (__bf16)1.0f : (__bf16)0.0f;
        #pragma unroll
        for (int i = 0; i < 8; i++) bones[i] = o;
    }

    f32x4 O[4] = {};
    f32x4 Osum = {};

    for (int t = 0; t < ntiles; t++) {
        __syncthreads();

        *(uint4*)&k_s[srow][sq]     = kr0;
        *(uint4*)&k_s[srow][sq + 8] = kr1;
        {
            __bf16 vtmp[16];
            *(uint4*)&vtmp[0] = vr0; *(uint4*)&vtmp[8] = vr1;
            #pragma unroll
            for (int i = 0; i < 16; i++) v_s[sq + i][srow] = vtmp[i];  // V^T
        }
        __syncthreads();

        if (t + 1 < ntiles) {
            int jr = j_lo + (t + 1) * 64 + srow; if (jr > N_SEQ - 1) jr = N_SEQ - 1;
            const uint4* ks = (const uint4*)(qkv + (size_t)jr * 3072 + 1024 + h * HD + sq);
            kr0 = ks[0]; kr1 = ks[1];
            const uint4* vs = (const uint4*)(qkv + (size_t)jr * 3072 + 2048 + h * HD + sq);
            vr0 = vs[0]; vr1 = vs[1];
        }

        const int j0 = j_lo + t * 64;

        f32x4 S[4] = {};
        __builtin_amdgcn_s_setprio(1);
        #pragma unroll
        for (int nt = 0; nt < 4; nt++) {
            bf16x8 b0 = *(const bf16x8*)&k_s[nt * 16 + l15][quad * 8];
            bf16x8 b1 = *(const bf16x8*)&k_s[nt * 16 + l15][quad * 8 + 32];
            S[nt] = MFMA16(aq0, b0, S[nt]);
            S[nt] = MFMA16(aq1, b1, S[nt]);
        }
        __builtin_amdgcn_s_setprio(0);

        #pragma unroll
        for (int nt = 0; nt < 4; nt++) {
            int jg = j0 + nt * 16 + l15;
            #pragma unroll
            for (int ri = 0; ri < 4; ri++) {
                int r_loc = wid * 16 + quad * 4 + ri;
                int e = jg - (q0 + r_loc) + 99;
                float v = -3.0e38f;
                if ((unsigned)e < (unsigned)NREL && jg < N_SEQ)
                    v = S[nt][ri] * 0.125f + (float)P_s[r_loc][e];
                float p = __expf(v);   // masked -> 0
                p_s[r_loc][nt * 16 + l15] = (__bf16)p;   // wave-private stripe
            }
        }

        bf16x8 ap0 = *(const bf16x8*)&p_s[wid * 16 + l15][quad * 8];
        bf16x8 ap1 = *(const bf16x8*)&p_s[wid * 16 + l15][quad * 8 + 32];
        __builtin_amdgcn_s_setprio(1);
        #pragma unroll
        for (int nt = 0; nt < 4; nt++) {
            bf16x8 b0 = *(const bf16x8*)&v_s[nt * 16 + l15][quad * 8];
            bf16x8 b1 = *(const bf16x8*)&v_s[nt * 16 + l15][quad * 8 + 32];
            O[nt] = MFMA16(ap0, b0, O[nt]);
            O[nt] = MFMA16(ap1, b1, O[nt]);
        }
        Osum = MFMA16(ap0, bones, Osum);
        Osum = MFMA16(ap1, bones, Osum);
        __builtin_amdgcn_s_setprio(0);
    }

    #pragma unroll
    for (int ri = 0; ri < 4; ri++) {
        float s = __shfl(Osum[ri], (lane & 48), 64);
        float inv = 1.0f / s;
        #pragma unroll
        for (int nt = 0; nt < 4; nt++) {
            int r = q0 + wid * 16 + quad * 4 + ri;
            qkv[(size_t)r * 3072 + h * HD + nt * 16 + l15] =
                __float2bfloat16(O[nt][ri] * inv);
        }
    }
}

extern "C" void kernel_launch(void* const* d_in, const int* in_sizes, int n_in,
                              void* d_out, int out_size, void* d_ws, size_t ws_size,
                              hipStream_t stream)
{
    (void)out_size; (void)ws_size; (void)n_in;

    const float *x = nullptr, *qkv_w = nullptr, *qkv_b = nullptr;
    const float *proj_w = nullptr, *proj_b = nullptr, *rel = nullptr;
    for (int i = 0; i < 6; i++) {
        switch (in_sizes[i]) {
            case 2097152: x      = (const float*)d_in[i]; break;
            case 3145728: qkv_w  = (const float*)d_in[i]; break;
            case 3072:    qkv_b  = (const float*)d_in[i]; break;
            case 1048576: proj_w = (const float*)d_in[i]; break;
            case 1024:    proj_b = (const float*)d_in[i]; break;
            case 203776:  rel    = (const float*)d_in[i]; break;
            default: break;
        }
    }

    char* ws = (char*)d_ws;
    __hip_bfloat16* qkv = (__hip_bfloat16*)ws;              // [2048][3072] 12.58 MB
    __bf16* xb  = (__bf16*)(ws + 12582912);                 // x bf16     4.19 MB
    __bf16* wb  = (__bf16*)(ws + 16777216);                 // qkv_w bf16 6.29 MB
    __bf16* pwb = (__bf16*)(ws + 23068672);                 // proj_w bf16 2.10 MB
    float* out = (float*)d_out;                             // [2048][1024] fp32

    // x + qkv_w conversion only (proj_w folded into attn tail blocks)
    cvt3<<<dim3((2097152 + 3145728) / 8 / 256), 256, 0, stream>>>(
        x, xb, 2097152, qkv_w, wb, 3145728, proj_w, pwb);
    gemm_db<128, 96, true><<<dim3(3072 / 96, N_SEQ / 128), 256, 0, stream>>>(
        xb, wb, qkv_b, (void*)qkv, DMODEL, 3072, DMODEL, 3072);
    attn_band_mfma<<<dim3(NHEAD * (N_SEQ / 64) + 16), 256, 0, stream>>>(
        qkv, rel, proj_w, pwb);
    gemm_db<64, 64, false><<<dim3(DMODEL / 64, N_SEQ / 64), 256, 0, stream>>>(
        (const __bf16*)qkv, pwb, proj_b, (void*)out, 3072, DMODEL, DMODEL, DMODEL);
}